// Round 1
// baseline (25.661 us; speedup 1.0000x reference)
//
#include <hip/hip_runtime.h>

// MLPKANLayer: per-(in,out) scalar MLP 1->H1(2)->H2(2)->1, relu, summed over in.
// x:[8192,64] f32 -> out:[8192,64] f32.
// Inputs (setup_inputs order): x, w1[i][o][2], b1[i][o][2], w2[i][o][2][2],
//                              b2[i][o][2], w3[i][o][2], b3[i][o]
//
// Structure: block = 256 threads (4 waves). Lane = o (0..63) so each wave
// covers all 64 outputs for a set of batch rows -> x[b,i] is wave-uniform
// (LDS broadcast read), weight loads are coalesced float2/float4 per lane.
// Each thread keeps BT_PER_WAVE=4 row accumulators in registers so the 6
// weight loads per (i,o) amortize over 4 connections.

#define IN_SIZE  64
#define OUT_SIZE 64
#define BATCH    8192

constexpr int BT_PER_WAVE = 4;
constexpr int WAVES_PER_BLOCK = 4;
constexpr int BT = BT_PER_WAVE * WAVES_PER_BLOCK;   // 16 batch rows / block

__global__ __launch_bounds__(256) void kan_kernel(
    const float* __restrict__ x,
    const float* __restrict__ w1, const float* __restrict__ b1,
    const float* __restrict__ w2, const float* __restrict__ b2,
    const float* __restrict__ w3, const float* __restrict__ b3,
    float* __restrict__ out)
{
    const int tid   = threadIdx.x;
    const int o     = tid & 63;        // output index = lane
    const int wv    = tid >> 6;        // wave id in block
    const int brow0 = blockIdx.x * BT; // first batch row of this block

    __shared__ float xs[BT * IN_SIZE]; // 16*64*4B = 4 KiB

    // Stage the x tile: BT*64 floats = 256 float4, one per thread. Coalesced.
    {
        const float4* xg = reinterpret_cast<const float4*>(x + brow0 * IN_SIZE);
        reinterpret_cast<float4*>(xs)[tid] = xg[tid];
    }
    __syncthreads();

    float acc[BT_PER_WAVE];
    #pragma unroll
    for (int r = 0; r < BT_PER_WAVE; ++r) acc[r] = 0.f;
    float bacc = 0.f;  // sum_i b3[i][o] — row-independent, hoisted out of r-loop

    const float* xw = xs + (wv * BT_PER_WAVE) * IN_SIZE;

    #pragma unroll 2
    for (int i = 0; i < IN_SIZE; ++i) {
        const int base = i * OUT_SIZE + o;
        const float2 W1 = reinterpret_cast<const float2*>(w1)[base];
        const float2 B1 = reinterpret_cast<const float2*>(b1)[base];
        const float4 W2 = reinterpret_cast<const float4*>(w2)[base]; // [k0h0,k0h1,k1h0,k1h1]
        const float2 B2 = reinterpret_cast<const float2*>(b2)[base];
        const float2 W3 = reinterpret_cast<const float2*>(w3)[base];
        const float  B3 = b3[base];
        bacc += B3;

        #pragma unroll
        for (int r = 0; r < BT_PER_WAVE; ++r) {
            const float xv = xw[r * IN_SIZE + i];   // wave-uniform -> LDS broadcast
            // layer 1 (fan_in = 1): h = relu(x*w1 + b1)
            const float h0 = fmaxf(fmaf(xv, W1.x, B1.x), 0.f);
            const float h1 = fmaxf(fmaf(xv, W1.y, B1.y), 0.f);
            // layer 2: u[k] = relu(sum_h h[h]*w2[k][h] + b2[k])
            float u0 = fmaf(h1, W2.y, fmaf(h0, W2.x, B2.x));
            float u1 = fmaf(h1, W2.w, fmaf(h0, W2.z, B2.y));
            u0 = fmaxf(u0, 0.f);
            u1 = fmaxf(u1, 0.f);
            // layer 3: y = u0*w3[0] + u1*w3[1] (+ b3 via bacc)
            acc[r] = fmaf(u0, W3.x, acc[r]);
            acc[r] = fmaf(u1, W3.y, acc[r]);
        }
    }

    #pragma unroll
    for (int r = 0; r < BT_PER_WAVE; ++r) {
        out[(brow0 + wv * BT_PER_WAVE + r) * OUT_SIZE + o] = acc[r] + bacc;
    }
}

extern "C" void kernel_launch(void* const* d_in, const int* in_sizes, int n_in,
                              void* d_out, int out_size, void* d_ws, size_t ws_size,
                              hipStream_t stream) {
    const float* x  = (const float*)d_in[0];
    const float* w1 = (const float*)d_in[1];
    const float* b1 = (const float*)d_in[2];
    const float* w2 = (const float*)d_in[3];
    const float* b2 = (const float*)d_in[4];
    const float* w3 = (const float*)d_in[5];
    const float* b3 = (const float*)d_in[6];
    float* out = (float*)d_out;

    const int grid = BATCH / BT;   // 512 blocks
    kan_kernel<<<grid, 256, 0, stream>>>(x, w1, b1, w2, b2, w3, b3, out);
}

// Round 3
// 18.005 us; speedup vs baseline: 1.4252x; 1.4252x over previous
//
#include <hip/hip_runtime.h>

// MLPKANLayer: per-(in,out) scalar MLP 1->2->2->1 (relu), summed over in.
// x:[8192,64] f32 -> out:[8192,64] f32.
// Inputs: x, w1[i][o][2], b1[i][o][2], w2[i][o][2][2], b2[i][o][2],
//         w3[i][o][2], b3[i][o]
//
// R1 structure: block = 512 threads (8 waves), lane = o. Each wave owns an
// i-chunk of 8 (weights register-resident: 8 x 13 = 104 VGPRs/lane, loaded
// ONCE per block) and processes BT=16 batch rows; per-row partial sums are
// combined across the 8 waves via a padded LDS array (stride 9 -> odd float
// stride -> conflict-free). Inner loop is pure VALU + wave-uniform LDS
// broadcast reads of x. Grid = 512 blocks = 2 blocks/CU = 4 waves/SIMD.
// (R2 = R1 resubmitted verbatim: previous bench died on an unresponsive
// container before any measurement.)

#define IN_SIZE  64
#define OUT_SIZE 64
#define BATCH    8192

constexpr int I_CHUNK = 8;                 // i's per wave
constexpr int WAVES   = 8;                 // waves per block (I_CHUNK*WAVES = 64)
constexpr int BT      = 16;                // batch rows per block
constexpr int PAD     = 9;                 // partial[r][o][PAD] stride (odd -> no bank conflict)

__device__ __forceinline__ void conn(float xv, float2 W1, float2 B1,
                                     float4 W2, float2 B2, float2 W3,
                                     float& s) {
    const float h0 = fmaxf(fmaf(xv, W1.x, B1.x), 0.f);
    const float h1 = fmaxf(fmaf(xv, W1.y, B1.y), 0.f);
    float u0 = fmaf(h1, W2.y, fmaf(h0, W2.x, B2.x));
    float u1 = fmaf(h1, W2.w, fmaf(h0, W2.z, B2.y));
    u0 = fmaxf(u0, 0.f);
    u1 = fmaxf(u1, 0.f);
    s = fmaf(u0, W3.x, s);
    s = fmaf(u1, W3.y, s);
}

__global__ __launch_bounds__(512, 4) void kan_kernel(
    const float* __restrict__ x,
    const float* __restrict__ w1, const float* __restrict__ b1,
    const float* __restrict__ w2, const float* __restrict__ b2,
    const float* __restrict__ w3, const float* __restrict__ b3,
    float* __restrict__ out)
{
    const int tid   = threadIdx.x;
    const int o     = tid & 63;
    const int wv    = tid >> 6;
    const int brow0 = blockIdx.x * BT;

    __shared__ float xs[BT * IN_SIZE];             // 4 KiB
    __shared__ float ps[BT * OUT_SIZE * PAD];      // 36 KiB

    // Stage x tile: 1024 floats, 512 threads -> one float2 each. Coalesced.
    {
        const float2* xg = reinterpret_cast<const float2*>(x + brow0 * IN_SIZE);
        reinterpret_cast<float2*>(xs)[tid] = xg[tid];
    }

    // Preload this wave's i-chunk weights into registers (coalesced per lane=o).
    const int i0 = wv * I_CHUNK;
    float2 W1[I_CHUNK], B1[I_CHUNK], B2[I_CHUNK], W3[I_CHUNK];
    float4 W2[I_CHUNK];
    float bacc = 0.f;
    #pragma unroll
    for (int ic = 0; ic < I_CHUNK; ++ic) {
        const int base = (i0 + ic) * OUT_SIZE + o;
        W1[ic] = reinterpret_cast<const float2*>(w1)[base];
        B1[ic] = reinterpret_cast<const float2*>(b1)[base];
        W2[ic] = reinterpret_cast<const float4*>(w2)[base];
        B2[ic] = reinterpret_cast<const float2*>(b2)[base];
        W3[ic] = reinterpret_cast<const float2*>(w3)[base];
        bacc  += b3[base];
    }

    __syncthreads();  // xs ready

    #pragma unroll
    for (int r = 0; r < BT; ++r) {
        // 8 wave-uniform x values for this row's i-chunk (broadcast reads).
        const float4 xa = *reinterpret_cast<const float4*>(xs + r * IN_SIZE + i0);
        const float4 xb = *reinterpret_cast<const float4*>(xs + r * IN_SIZE + i0 + 4);
        float s = bacc;
        conn(xa.x, W1[0], B1[0], W2[0], B2[0], W3[0], s);
        conn(xa.y, W1[1], B1[1], W2[1], B2[1], W3[1], s);
        conn(xa.z, W1[2], B1[2], W2[2], B2[2], W3[2], s);
        conn(xa.w, W1[3], B1[3], W2[3], B2[3], W3[3], s);
        conn(xb.x, W1[4], B1[4], W2[4], B2[4], W3[4], s);
        conn(xb.y, W1[5], B1[5], W2[5], B2[5], W3[5], s);
        conn(xb.z, W1[6], B1[6], W2[6], B2[6], W3[6], s);
        conn(xb.w, W1[7], B1[7], W2[7], B2[7], W3[7], s);
        ps[(r * OUT_SIZE + o) * PAD + wv] = s;
    }

    __syncthreads();

    // Reduce 8 wave-partials per (r,o). 1024 outputs, 512 threads -> 2 each.
    #pragma unroll
    for (int t = tid; t < BT * OUT_SIZE; t += 512) {
        const float* p = ps + t * PAD;
        const float v = ((p[0] + p[1]) + (p[2] + p[3]))
                      + ((p[4] + p[5]) + (p[6] + p[7]));
        out[brow0 * OUT_SIZE + t] = v;   // t = r*64+o, rows contiguous
    }
}

extern "C" void kernel_launch(void* const* d_in, const int* in_sizes, int n_in,
                              void* d_out, int out_size, void* d_ws, size_t ws_size,
                              hipStream_t stream) {
    const float* x  = (const float*)d_in[0];
    const float* w1 = (const float*)d_in[1];
    const float* b1 = (const float*)d_in[2];
    const float* w2 = (const float*)d_in[3];
    const float* b2 = (const float*)d_in[4];
    const float* w3 = (const float*)d_in[5];
    const float* b3 = (const float*)d_in[6];
    float* out = (float*)d_out;

    const int grid = BATCH / BT;   // 512 blocks x 512 threads
    kan_kernel<<<grid, 512, 0, stream>>>(x, w1, b1, w2, b2, w3, b3, out);
}